// Round 7
// baseline (5424.540 us; speedup 1.0000x reference)
//
#include <hip/hip_runtime.h>
#include <cstdint>
#include <cstddef>

// Problem constants
#define N_NEU   4096
#define N_IN    1024
#define B_SZ    8
#define T_STEPS 500
#define NSLICE  16
#define NBLK    (B_SZ * NSLICE)     // 128 sim blocks, 256 threads, 1 post/thread
#define PROD_BLKS 128               // producer blocks (FF drive), 4 waves each
#define FF_WORDS (B_SZ * T_STEPS * 16)

// ws layout:
//   [0)      u64 tmask[64]            512 B  (per-64-group exc-type bit masks)
//   [512)    int prog[512]            2 KB   (per-(b,chunk) FF progress tags)
//   [2560)   u64 mb2[2][8][64][2]     16 KB  (tagged dbuf spike words)
//   [18944)  u64 ffmask[B*T*16]       512 KB (input-spike bitmasks)
//   [530944) float ffdrive[T][B][N]   65.5 MB (FF drive, producer-filled)
#define WS_TM_OFF   0
#define WS_PROG_OFF 512
#define WS_MB_OFF   2560
#define WS_FFM_OFF  18944
#define WS_FFD_OFF  530944
#define WS_NEED_FFD (530944 + (size_t)T_STEPS * B_SZ * N_NEU * 4)

__global__ __launch_bounds__(64) void snn_init(const int* __restrict__ ci,
                                               unsigned long long* __restrict__ tmask,
                                               unsigned long long* __restrict__ mb2,
                                               int* __restrict__ prog) {
    const int k = blockIdx.x, l = threadIdx.x;   // 64 blocks x 64 threads
    unsigned long long m = __ballot(ci[(k << 6) + l] == 0);
    if (l == 0) tmask[k] = m;
    const int idx = (k << 6) + l;
    if (idx < 2048) mb2[idx] = 0ULL;             // tag 0 never matches t>=1
    if (idx < 512)  prog[idx] = 0;               // FF progress: nothing ready
}

// input spikes (B,T,NI) -> bitmask words, 64 elems per word, ascending order
__global__ __launch_bounds__(256) void snn_ffmask(const float* __restrict__ inspk,
                                                  unsigned long long* __restrict__ ffmask) {
    int gid = blockIdx.x * 256 + threadIdx.x;
    int wid = gid >> 6, lane = gid & 63;
    int nw  = (gridDim.x * 256) >> 6;
    for (int w = wid; w < FF_WORDS; w += nw) {
        float v = inspk[(size_t)w * 64 + lane];
        unsigned long long m = __ballot(v > 0.5f);
        if (lane == 0) ffmask[w] = m;
    }
}

// Extract set-bit indices of a distributed 64x64-bit mask (lane l holds word l,
// bit b -> index l*64+b) into lds as typed entries (idx<<2)|ty, globally
// ascending; ty from tm_exc (bit set -> ty0/exc, clear -> ty1/inh). Pads to a
// multiple of 64 with sentinel entries (idx 0, ty 2). Returns real count.
__device__ __forceinline__ int extract_pad(unsigned long long m,
                                           unsigned long long tm_exc,
                                           int* lds, int lane) {
    int pc  = __popcll(m);
    int sum = pc;
#pragma unroll
    for (int d = 1; d < 64; d <<= 1) {
        int o = __shfl_up(sum, d, 64);
        if (lane >= d) sum += o;
    }
    int off   = sum - pc;           // exclusive prefix
    int total = __shfl(sum, 63, 64);
    int base  = lane << 6;
    while (m) {
        int bit = __builtin_ctzll(m);
        int ty  = ((tm_exc >> bit) & 1ULL) ? 0 : 1;
        lds[off++] = ((base + bit) << 2) | ty;
        m &= m - 1ULL;
    }
    int padcnt = (-total) & 63;
    if (lane < padcnt) lds[total + lane] = 2;   // sentinel: idx 0, ty 2
    return total;
}

// Combined typed gather: 64-deep pipelined loop over a padded entry list;
// exc/inh accumulate into SEPARATE accumulators (each internally ascending ->
// bit-exact vs reference's separate matmuls). Sentinels (ty2) contribute 0.
// List reads widened to int4 (ds_read_b128); accumulation order untouched.
__device__ __forceinline__ void gather2(const int* __restrict__ lst, int npad,
                                        const float* __restrict__ base,
                                        float se, float si,
                                        float* oe, float* oi) {
#pragma clang fp contract(off)
    float ae = 0.0f, ai = 0.0f;
    const int4* lst4 = (const int4*)lst;
    for (int k = 0; k < npad; k += 64) {
        int4  eq[16];
        int   e[64];
        float w[64];
#pragma unroll
        for (int u = 0; u < 16; ++u) eq[u] = lst4[(k >> 2) + u];
#pragma unroll
        for (int u = 0; u < 16; ++u) {
            e[4 * u + 0] = eq[u].x; e[4 * u + 1] = eq[u].y;
            e[4 * u + 2] = eq[u].z; e[4 * u + 3] = eq[u].w;
        }
#pragma unroll
        for (int u = 0; u < 64; ++u) w[u] = base[(size_t)(e[u] >> 2) << 12];
#pragma unroll
        for (int u = 0; u < 64; ++u) {
            const int ty = e[u] & 3;
            const float sc = (ty == 0) ? se : ((ty == 1) ? si : 0.0f);
            const float p  = w[u] * sc;           // per-element product rounding = W_eff
            ae = (ty == 0) ? ae + p : ae;
            ai = (ty == 1) ? ai + p : ai;
        }
    }
    *oe = ae; *oi = ai;
}

__global__ __launch_bounds__(256) void snn_run(
    const float* __restrict__ W,       // (N,N) row j = presyn
    const float* __restrict__ Wff,     // (NI,N)
    const float* __restrict__ sf,      // (2,2)
    const float* __restrict__ sfff,    // (1,2)
    const int*   __restrict__ ci,      // (N)
    float*       __restrict__ out,     // (B,T,N)
    const unsigned long long* __restrict__ ffmask,
    const unsigned long long* __restrict__ tmask_g,
    float*       __restrict__ ffdrive, // producer-filled in this dispatch
    int use_ffpre,
    unsigned long long* __restrict__ mb2,
    int*         __restrict__ prog)
{
#pragma clang fp contract(off)
    const int tid   = threadIdx.x;
    const int lane  = tid & 63;
    const int wv    = tid >> 6;
    const int bid   = blockIdx.x;

    // Per-wave private LDS regions: NO cross-wave sharing -> no barriers.
    __shared__ alignas(16) int lds_c[4][N_NEU + 64];
    __shared__ alignas(16) int lds_f[4][N_IN + 64];

    // ================= producer role: fill ffdrive on idle CUs =============
    // 128 producer blocks x 4 waves = 512 waves; wave pw owns (b,chunk) =
    // (pw>>6, pw&63) and sweeps t ascending. Rate ~1100-1500 cy/t < sim's
    // ~2570 cy/step -> producers stay permanently ahead after t=0 ramp.
    // Producers never wait on sim (no deadlock cycle); 256 blocks on 256 CUs
    // all co-resident (sim 84KB + prod LDS both fit everywhere).
    if (bid >= NBLK) {
        const int pidx = bid - NBLK;
        const int pw   = (pidx << 2) | wv;       // 0..511
        const int pb   = pw >> 6;                // batch
        const int pch  = pw & 63;                // 64-neuron chunk
        const int pi   = (pch << 6) + lane;
        const float ps_ff = sfff[ci[pi]];
        int* const plds = lds_f[wv];
        for (int t = 0; t < T_STEPS; ++t) {
            const unsigned long long mf =
                (lane < 16) ? ffmask[((size_t)pb * T_STEPS + t) * 16 + lane] : 0ULL;
            const int n = extract_pad(mf, ~0ULL, plds, lane);   // all ty0
            float fd, dummy;
            // identical op sequence to the old snn_ffpre => bit-exact fd
            gather2(plds, (n + 63) & ~63, Wff + pi, ps_ff, 0.0f, &fd, &dummy);
            __hip_atomic_store(&ffdrive[((size_t)t * B_SZ + pb) * N_NEU + pi],
                               fd, __ATOMIC_RELAXED, __HIP_MEMORY_SCOPE_AGENT);
            if (lane == 0)
                __hip_atomic_store(&prog[pw], t + 1,
                                   __ATOMIC_RELEASE, __HIP_MEMORY_SCOPE_AGENT);
            // release orders the wave's data stores into LLC before the tag.
        }
        return;
    }

    // ================= sim role (critical path unchanged from R6) ==========
    // slice from bits {0,1,2,6}, batch from bits {3,4,5}
    const int slice = (((bid >> 6) & 1) << 3) | (bid & 7);
    const int b     = (bid >> 3) & 7;
    const int i     = (slice << 8) + (wv << 6) + lane;    // my post neuron
    const int c     = ci[i];

    const float s_exc = sf[c];
    const float s_inh = sf[2 + c];
    const float s_ff  = sfff[c];

    const unsigned long long my_tm = tmask_g[lane];
    int* const my_ldsc = lds_c[wv];
    int* const my_ldsf = lds_f[wv];

    // mb2 layout (u64 units): [parity][batch][entry=(slice<<2)|wv][half]
    unsigned long long* const mbB = mb2 + (size_t)b * 128;
    const int myprog = (b << 6) | (slice << 2) | wv;      // my (b,chunk) flag

    float v = -70.0f, rf = 0.0f;
    float h0 = 0.0f, h1 = 0.0f, h2 = 0.0f, h3 = 0.0f;
    float g0 = 0.0f, g1 = 0.0f, g2 = 0.0f, g3 = 0.0f;

    const float aR0 = expf(-0.1f / 0.5f);
    const float aR1 = expf(-0.1f / 2.0f);
    const float aD0 = expf(-0.1f / 2.0f);
    const float aD1 = expf(-0.1f / 100.0f);
    const float aD2 = expf(-0.1f / 5.0f);
    const float kmem   = c ? (0.1f / 10.0f) : (0.1f / 20.0f);
    const float rsteps = c ? 10.0f : 20.0f;

    // warming base: this wave's 256B segment start within any W row
    const float* const wseg = W + (size_t)((slice << 8) + (wv << 6));

    for (int t = 0; t < T_STEPS; ++t) {
        unsigned long long mw = 0ULL;
        if (t > 0) {
            // spike poll (tags, payload-in-word) merged with lane0's FF
            // progress check (prog >= t+1 before ffdrive[t] is readable).
            const unsigned int tg = (unsigned int)t;
            const unsigned long long* ep =
                mbB + (size_t)(t & 1) * 1024 + ((size_t)lane << 1);
            unsigned long long w0, w1;
            for (;;) {
                w0 = __hip_atomic_load(&ep[0], __ATOMIC_RELAXED,
                                       __HIP_MEMORY_SCOPE_AGENT);
                w1 = __hip_atomic_load(&ep[1], __ATOMIC_RELAXED,
                                       __HIP_MEMORY_SCOPE_AGENT);
                int pg = 0x7fffffff;
                if (use_ffpre && lane == 0)
                    pg = __hip_atomic_load(&prog[myprog], __ATOMIC_RELAXED,
                                           __HIP_MEMORY_SCOPE_AGENT);
                const bool ok = ((unsigned int)(w0 >> 32) == tg) &&
                                ((unsigned int)(w1 >> 32) == tg) &&
                                (pg >= t + 1);
                if (__ballot(ok) == ~0ULL) break;
                __builtin_amdgcn_s_sleep(1);
            }
            mw = (w0 & 0xFFFFFFFFULL) | ((w1 & 0xFFFFFFFFULL) << 32);
            asm volatile("" ::: "memory");   // keep later mem ops below poll
        } else if (use_ffpre) {
            // t=0 ramp: wait for my producer's first tile (~1500 cy, once).
            for (;;) {
                int pg = 1;
                if (lane == 0)
                    pg = __hip_atomic_load(&prog[myprog], __ATOMIC_RELAXED,
                                           __HIP_MEMORY_SCOPE_AGENT);
                if (__ballot(pg >= 1) == ~0ULL) break;
                __builtin_amdgcn_s_sleep(1);
            }
            asm volatile("" ::: "memory");
        }

        // FF drive: agent-scope load (LLC-coherent vs producer's release).
        // Issued immediately after the poll; latency hides under warming +
        // extract + gather below.
        float ffd = 0.0f;
        if (use_ffpre) {
            ffd = __hip_atomic_load(&ffdrive[((size_t)t * B_SZ + b) * N_NEU + i],
                                    __ATOMIC_RELAXED, __HIP_MEMORY_SCOPE_AGENT);
            asm volatile("" :: "v"(ffd));
        }

        // ---- line warming: pull this step's W row-segments toward L1 while
        // the extract scan runs; real gather loads MSHR-merge.
        {
            unsigned long long mm = mw;
            float wacc = 0.0f;
            const size_t rowbase = (size_t)lane << 18;  // (lane*64)<<12 floats
            while (mm) {
                const int bit = __builtin_ctzll(mm); mm &= mm - 1ULL;
                const float* r = wseg + rowbase + ((size_t)bit << 12);
                wacc += r[0]; wacc += r[16]; wacc += r[32]; wacc += r[48];
            }
            asm volatile("" :: "v"(wacc));
        }

        // zero-skip: fully-silent network step -> no extract scan needed.
        int ne = 0;
        if (__ballot(mw != 0ULL) != 0ULL)
            ne = extract_pad(mw, my_tm, my_ldsc, lane);

        if (!use_ffpre) {
            const unsigned long long mf =
                (lane < 16) ? ffmask[((size_t)b * T_STEPS + t) * 16 + lane] : 0ULL;
            const int nf = extract_pad(mf, ~0ULL, my_ldsf, lane);
            float fd, dummy;
            gather2(my_ldsf, (nf + 63) & ~63, Wff + i, s_ff, 0.0f, &fd, &dummy);
            ffd = fd;
        }

        float exc, inh;
        gather2(my_ldsc, (ne + 63) & ~63, W + i, s_exc, s_inh, &exc, &inh);

        // ---- neuron update (identical fp op sequence to R0-R6: bit-exact) ----
        const float d0 = exc;
        const float d1 = 0.5f * exc;
        const float d2 = inh;
        const float d3 = ffd;

        h0 = fmaf(h0, aR0, d0);
        h1 = fmaf(h1, aR1, d1);
        h2 = fmaf(h2, aR0, d2);
        h3 = fmaf(h3, aR0, d3);
        g0 = fmaf(g0, aD0, (1.0f - aD0) * h0);
        g1 = fmaf(g1, aD1, (1.0f - aD1) * h1);
        g2 = fmaf(g2, aD2, (1.0f - aD2) * h2);
        g3 = fmaf(g3, aD0, (1.0f - aD0) * h3);

        const float p0 = g0 * (0.0f - v);
        const float p1 = g1 * (0.0f - v);
        const float p2 = g2 * (-80.0f - v);
        const float p3 = g3 * (0.0f - v);
        const float Isyn = ((p0 + p1) + p2) + p3;

        float vn = fmaf(kmem, (-70.0f - v) + Isyn / 10.0f, v);
        const bool refr = rf > 0.0f;
        if (refr) vn = -65.0f;
        const float sn = (!refr && (vn > -50.0f)) ? 1.0f : 0.0f;
        const bool spk = sn > 0.5f;

        // publish at the EARLIEST instant: right after the spike decision.
        const unsigned long long sm = __ballot(spk);
        if (lane == 0) {
            const unsigned long long tg =
                (unsigned long long)(unsigned int)(t + 1) << 32;
            unsigned long long* pp = mb2 + (size_t)((t + 1) & 1) * 1024
                                   + (size_t)b * 128
                                   + ((size_t)((slice << 2) | wv) << 1);
            __hip_atomic_store(&pp[0], tg | (sm & 0xFFFFFFFFULL),
                               __ATOMIC_RELAXED, __HIP_MEMORY_SCOPE_AGENT);
            __hip_atomic_store(&pp[1], tg | (sm >> 32),
                               __ATOMIC_RELAXED, __HIP_MEMORY_SCOPE_AGENT);
        }

        v  = spk ? -65.0f : vn;
        rf = spk ? rsteps : fmaxf(rf - 1.0f, 0.0f);
        out[((size_t)b * T_STEPS + t) * N_NEU + i] = sn;   // regular store
    }
}

extern "C" void kernel_launch(void* const* d_in, const int* in_sizes, int n_in,
                              void* d_out, int out_size, void* d_ws, size_t ws_size,
                              hipStream_t stream) {
    const float* inspk = (const float*)d_in[0];
    const float* W     = (const float*)d_in[1];
    const float* Wff   = (const float*)d_in[2];
    const float* sf    = (const float*)d_in[3];
    const float* sfff  = (const float*)d_in[4];
    const int*   ci    = (const int*)d_in[5];

    float* out = (float*)d_out;
    unsigned long long* tmask   = (unsigned long long*)((char*)d_ws + WS_TM_OFF);
    int*                prog    = (int*)((char*)d_ws + WS_PROG_OFF);
    unsigned long long* mb2     = (unsigned long long*)((char*)d_ws + WS_MB_OFF);
    unsigned long long* ffmask  = (unsigned long long*)((char*)d_ws + WS_FFM_OFF);
    float*              ffdrive = (float*)((char*)d_ws + WS_FFD_OFF);
    const int use_ffpre = (ws_size >= WS_NEED_FFD) ? 1 : 0;

    snn_init<<<64, 64, 0, stream>>>(ci, tmask, mb2, prog);
    snn_ffmask<<<1000, 256, 0, stream>>>(inspk, ffmask);
    const int grid = NBLK + (use_ffpre ? PROD_BLKS : 0);
    snn_run<<<grid, 256, 0, stream>>>(W, Wff, sf, sfff, ci, out,
                                      ffmask, tmask, ffdrive, use_ffpre,
                                      mb2, prog);
}

// Round 8
// 1622.873 us; speedup vs baseline: 3.3426x; 3.3426x over previous
//
#include <hip/hip_runtime.h>
#include <cstdint>
#include <cstddef>

// Problem constants
#define N_NEU   4096
#define N_IN    1024
#define B_SZ    8
#define T_STEPS 500
#define NSLICE  16
#define NBLK    (B_SZ * NSLICE)     // 128 sim blocks, 256 threads, 1 post/thread
#define PROD_BLKS 128               // producer blocks (FF drive), 4 waves each
#define FF_WORDS (B_SZ * T_STEPS * 16)
#define FFD_DEPTH 4                 // ffd2 rotation depth (producer lead <= 4)

// ws layout:
//   [0)      u64 tmask[64]            512 B  (per-64-group exc-type bit masks)
//   [512)    u64 mb2[2][8][64][2]     16 KB  (tagged dbuf spike words:
//                                            (tag<<32)|mask_half, 2 halves/wave)
//   [17408)  u64 ffmask[B*T*16]       512 KB (input-spike bitmasks)
//   [541696) u64 ffd2[4][8][4096]     1 MB   (tagged FF drive: (t+1)<<32|f32bits)
#define WS_TM_OFF   0
#define WS_MB_OFF   512
#define WS_FFM_OFF  17408
#define WS_FFD2_OFF 541696
#define WS_NEED     (541696 + (size_t)FFD_DEPTH * B_SZ * N_NEU * 8)

__global__ __launch_bounds__(64) void snn_init(const int* __restrict__ ci,
                                               unsigned long long* __restrict__ tmask,
                                               unsigned long long* __restrict__ mb2) {
    const int k = blockIdx.x, l = threadIdx.x;   // 64 blocks x 64 threads
    unsigned long long m = __ballot(ci[(k << 6) + l] == 0);
    if (l == 0) tmask[k] = m;
    const int idx = (k << 6) + l;
    if (idx < 2048) mb2[idx] = 0ULL;             // tag 0 never matches t>=1
}

// input spikes (B,T,NI) -> bitmask words; also clears ffd2 tag words.
__global__ __launch_bounds__(256) void snn_ffmask(const float* __restrict__ inspk,
                                                  unsigned long long* __restrict__ ffmask,
                                                  unsigned long long* __restrict__ ffd2) {
    int gid = blockIdx.x * 256 + threadIdx.x;
    if (gid < FFD_DEPTH * B_SZ * N_NEU) ffd2[gid] = 0ULL;  // tag 0: not ready
    int wid = gid >> 6, lane = gid & 63;
    int nw  = (gridDim.x * 256) >> 6;
    for (int w = wid; w < FF_WORDS; w += nw) {
        float v = inspk[(size_t)w * 64 + lane];
        unsigned long long m = __ballot(v > 0.5f);
        if (lane == 0) ffmask[w] = m;
    }
}

// Extract set-bit indices of a distributed 64x64-bit mask (lane l holds word l,
// bit b -> index l*64+b) into lds as typed entries (idx<<2)|ty, globally
// ascending; ty from tm_exc (bit set -> ty0/exc, clear -> ty1/inh). Pads to a
// multiple of 64 with sentinel entries (idx 0, ty 2). Returns real count.
__device__ __forceinline__ int extract_pad(unsigned long long m,
                                           unsigned long long tm_exc,
                                           int* lds, int lane) {
    int pc  = __popcll(m);
    int sum = pc;
#pragma unroll
    for (int d = 1; d < 64; d <<= 1) {
        int o = __shfl_up(sum, d, 64);
        if (lane >= d) sum += o;
    }
    int off   = sum - pc;           // exclusive prefix
    int total = __shfl(sum, 63, 64);
    int base  = lane << 6;
    while (m) {
        int bit = __builtin_ctzll(m);
        int ty  = ((tm_exc >> bit) & 1ULL) ? 0 : 1;
        lds[off++] = ((base + bit) << 2) | ty;
        m &= m - 1ULL;
    }
    int padcnt = (-total) & 63;
    if (lane < padcnt) lds[total + lane] = 2;   // sentinel: idx 0, ty 2
    return total;
}

// Combined typed gather: 64-deep pipelined loop over a padded entry list;
// exc/inh accumulate into SEPARATE accumulators (each internally ascending ->
// bit-exact vs reference's separate matmuls). Sentinels (ty2) contribute 0.
// List reads widened to int4 (ds_read_b128); accumulation order untouched.
__device__ __forceinline__ void gather2(const int* __restrict__ lst, int npad,
                                        const float* __restrict__ base,
                                        float se, float si,
                                        float* oe, float* oi) {
#pragma clang fp contract(off)
    float ae = 0.0f, ai = 0.0f;
    const int4* lst4 = (const int4*)lst;
    for (int k = 0; k < npad; k += 64) {
        int4  eq[16];
        int   e[64];
        float w[64];
#pragma unroll
        for (int u = 0; u < 16; ++u) eq[u] = lst4[(k >> 2) + u];
#pragma unroll
        for (int u = 0; u < 16; ++u) {
            e[4 * u + 0] = eq[u].x; e[4 * u + 1] = eq[u].y;
            e[4 * u + 2] = eq[u].z; e[4 * u + 3] = eq[u].w;
        }
#pragma unroll
        for (int u = 0; u < 64; ++u) w[u] = base[(size_t)(e[u] >> 2) << 12];
#pragma unroll
        for (int u = 0; u < 64; ++u) {
            const int ty = e[u] & 3;
            const float sc = (ty == 0) ? se : ((ty == 1) ? si : 0.0f);
            const float p  = w[u] * sc;           // per-element product rounding = W_eff
            ae = (ty == 0) ? ae + p : ae;
            ai = (ty == 1) ? ai + p : ai;
        }
    }
    *oe = ae; *oi = ai;
}

__global__ __launch_bounds__(256) void snn_run(
    const float* __restrict__ W,       // (N,N) row j = presyn
    const float* __restrict__ Wff,     // (NI,N)
    const float* __restrict__ sf,      // (2,2)
    const float* __restrict__ sfff,    // (1,2)
    const int*   __restrict__ ci,      // (N)
    float*       __restrict__ out,     // (B,T,N)
    const unsigned long long* __restrict__ ffmask,
    const unsigned long long* __restrict__ tmask_g,
    unsigned long long* __restrict__ ffd2,   // tagged FF drive, producer-filled
    int use_ffpre,
    unsigned long long* __restrict__ mb2)
{
#pragma clang fp contract(off)
    const int tid   = threadIdx.x;
    const int lane  = tid & 63;
    const int wv    = tid >> 6;
    const int bid   = blockIdx.x;

    // Per-wave private LDS regions: NO cross-wave sharing -> no barriers.
    __shared__ alignas(16) int lds_c[4][N_NEU + 64];
    __shared__ alignas(16) int lds_f[4][N_IN + 64];

    // ================= producer role: fill ffd2 on idle CUs ================
    // 512 producer waves, wave pw owns (b,chunk)=(pw>>6,pw&63), 1:1 partner =
    // sim wave (b, slice=chunk>>2, wv=chunk&3). ALL sync is via relaxed
    // tagged words (R7 lesson: agent-scope RELEASE = per-step L2 writeback
    // = 10x disaster). Back-pressure: before overwriting ffd2 slot t%4, wait
    // until partner's mb2 tag >= t-3 (partner consumed t-4). The gate check
    // runs AFTER the gather (compute overlaps the gate load); deadlock-free:
    // a sim wave stuck at t has published tag t, and t >= t-3 always.
    if (bid >= NBLK) {
        const int pidx = bid - NBLK;
        const int pw   = (pidx << 2) | wv;       // 0..511
        const int pb   = pw >> 6;                // batch
        const int pch  = pw & 63;                // 64-neuron chunk
        const int pi   = (pch << 6) + lane;
        const float ps_ff = sfff[ci[pi]];
        int* const plds = lds_f[wv];
        const unsigned long long* const pt0 =
            mb2 + (size_t)pb * 128 + ((size_t)pch << 1);   // parity0 word0
        const unsigned long long* const pt1 = pt0 + 1024;  // parity1 word0
        int lastTag = 0;
        for (int t = 0; t < T_STEPS; ++t) {
            const unsigned long long mf =
                (lane < 16) ? ffmask[((size_t)pb * T_STEPS + t) * 16 + lane] : 0ULL;
            const int n = extract_pad(mf, ~0ULL, plds, lane);   // all ty0
            float fd, dummy;
            // identical op sequence to the old snn_ffpre => bit-exact fd
            gather2(plds, (n + 63) & ~63, Wff + pi, ps_ff, 0.0f, &fd, &dummy);
            if (t >= FFD_DEPTH && lastTag < t - (FFD_DEPTH - 1)) {
                for (;;) {
                    unsigned long long a = __hip_atomic_load(pt0, __ATOMIC_RELAXED,
                                                             __HIP_MEMORY_SCOPE_AGENT);
                    unsigned long long c = __hip_atomic_load(pt1, __ATOMIC_RELAXED,
                                                             __HIP_MEMORY_SCOPE_AGENT);
                    const int ta = (int)(unsigned int)(a >> 32);
                    const int tb = (int)(unsigned int)(c >> 32);
                    lastTag = ta > tb ? ta : tb;
                    if (lastTag >= t - (FFD_DEPTH - 1)) break;
                    __builtin_amdgcn_s_sleep(1);
                }
            }
            const unsigned long long wd =
                ((unsigned long long)(unsigned int)(t + 1) << 32) |
                (unsigned long long)__float_as_uint(fd);
            __hip_atomic_store(&ffd2[(((size_t)(t & (FFD_DEPTH - 1))) * B_SZ + pb)
                                     * N_NEU + pi],
                               wd, __ATOMIC_RELAXED, __HIP_MEMORY_SCOPE_AGENT);
        }
        return;
    }

    // ================= sim role (critical path = R6) =======================
    // slice from bits {0,1,2,6}, batch from bits {3,4,5}
    const int slice = (((bid >> 6) & 1) << 3) | (bid & 7);
    const int b     = (bid >> 3) & 7;
    const int i     = (slice << 8) + (wv << 6) + lane;    // my post neuron
    const int c     = ci[i];

    const float s_exc = sf[c];
    const float s_inh = sf[2 + c];
    const float s_ff  = sfff[c];

    const unsigned long long my_tm = tmask_g[lane];
    int* const my_ldsc = lds_c[wv];
    int* const my_ldsf = lds_f[wv];

    // mb2 layout (u64 units): [parity][batch][entry=(slice<<2)|wv][half]
    unsigned long long* const mbB = mb2 + (size_t)b * 128;

    float v = -70.0f, rf = 0.0f;
    float h0 = 0.0f, h1 = 0.0f, h2 = 0.0f, h3 = 0.0f;
    float g0 = 0.0f, g1 = 0.0f, g2 = 0.0f, g3 = 0.0f;

    const float aR0 = expf(-0.1f / 0.5f);
    const float aR1 = expf(-0.1f / 2.0f);
    const float aD0 = expf(-0.1f / 2.0f);
    const float aD1 = expf(-0.1f / 100.0f);
    const float aD2 = expf(-0.1f / 5.0f);
    const float kmem   = c ? (0.1f / 10.0f) : (0.1f / 20.0f);
    const float rsteps = c ? 10.0f : 20.0f;

    // warming base: this wave's 256B segment start within any W row
    const float* const wseg = W + (size_t)((slice << 8) + (wv << 6));

    for (int t = 0; t < T_STEPS; ++t) {
        unsigned long long mw = 0ULL;
        float ffd = 0.0f;
        const unsigned long long* const fp =
            ffd2 + (((size_t)(t & (FFD_DEPTH - 1))) * B_SZ + b) * N_NEU + i;
        if (t > 0) {
            // merged poll: 2 spike words + my tagged ffd word. On tag match
            // the FF drive is ALREADY in the register (no extra hop).
            const unsigned int tg = (unsigned int)t;
            const unsigned long long* ep =
                mbB + (size_t)(t & 1) * 1024 + ((size_t)lane << 1);
            unsigned long long w0, w1, fw = 0ULL;
            for (;;) {
                w0 = __hip_atomic_load(&ep[0], __ATOMIC_RELAXED,
                                       __HIP_MEMORY_SCOPE_AGENT);
                w1 = __hip_atomic_load(&ep[1], __ATOMIC_RELAXED,
                                       __HIP_MEMORY_SCOPE_AGENT);
                bool ok = ((unsigned int)(w0 >> 32) == tg) &&
                          ((unsigned int)(w1 >> 32) == tg);
                if (use_ffpre) {
                    fw = __hip_atomic_load(fp, __ATOMIC_RELAXED,
                                           __HIP_MEMORY_SCOPE_AGENT);
                    ok = ok && ((unsigned int)(fw >> 32) == tg + 1);
                }
                if (__ballot(ok) == ~0ULL) break;
                __builtin_amdgcn_s_sleep(1);
            }
            mw = (w0 & 0xFFFFFFFFULL) | ((w1 & 0xFFFFFFFFULL) << 32);
            if (use_ffpre) ffd = __uint_as_float((unsigned int)fw);
            asm volatile("" ::: "memory");   // keep later mem ops below poll
        } else if (use_ffpre) {
            // t=0: spike mask is empty; wait only for producer's first tile.
            unsigned long long fw;
            for (;;) {
                fw = __hip_atomic_load(fp, __ATOMIC_RELAXED,
                                       __HIP_MEMORY_SCOPE_AGENT);
                if (__ballot((unsigned int)(fw >> 32) == 1u) == ~0ULL) break;
                __builtin_amdgcn_s_sleep(1);
            }
            ffd = __uint_as_float((unsigned int)fw);
            asm volatile("" ::: "memory");
        }

        // ---- line warming: pull this step's W row-segments toward L1 while
        // the extract scan runs; real gather loads MSHR-merge.
        {
            unsigned long long mm = mw;
            float wacc = 0.0f;
            const size_t rowbase = (size_t)lane << 18;  // (lane*64)<<12 floats
            while (mm) {
                const int bit = __builtin_ctzll(mm); mm &= mm - 1ULL;
                const float* r = wseg + rowbase + ((size_t)bit << 12);
                wacc += r[0]; wacc += r[16]; wacc += r[32]; wacc += r[48];
            }
            asm volatile("" :: "v"(wacc));
        }

        // zero-skip: fully-silent network step -> no extract scan needed.
        int ne = 0;
        if (__ballot(mw != 0ULL) != 0ULL)
            ne = extract_pad(mw, my_tm, my_ldsc, lane);

        if (!use_ffpre) {
            const unsigned long long mf =
                (lane < 16) ? ffmask[((size_t)b * T_STEPS + t) * 16 + lane] : 0ULL;
            const int nf = extract_pad(mf, ~0ULL, my_ldsf, lane);
            float fd, dummy;
            gather2(my_ldsf, (nf + 63) & ~63, Wff + i, s_ff, 0.0f, &fd, &dummy);
            ffd = fd;
        }

        float exc, inh;
        gather2(my_ldsc, (ne + 63) & ~63, W + i, s_exc, s_inh, &exc, &inh);

        // ---- neuron update (identical fp op sequence to R0-R7: bit-exact) ----
        const float d0 = exc;
        const float d1 = 0.5f * exc;
        const float d2 = inh;
        const float d3 = ffd;

        h0 = fmaf(h0, aR0, d0);
        h1 = fmaf(h1, aR1, d1);
        h2 = fmaf(h2, aR0, d2);
        h3 = fmaf(h3, aR0, d3);
        g0 = fmaf(g0, aD0, (1.0f - aD0) * h0);
        g1 = fmaf(g1, aD1, (1.0f - aD1) * h1);
        g2 = fmaf(g2, aD2, (1.0f - aD2) * h2);
        g3 = fmaf(g3, aD0, (1.0f - aD0) * h3);

        const float p0 = g0 * (0.0f - v);
        const float p1 = g1 * (0.0f - v);
        const float p2 = g2 * (-80.0f - v);
        const float p3 = g3 * (0.0f - v);
        const float Isyn = ((p0 + p1) + p2) + p3;

        float vn = fmaf(kmem, (-70.0f - v) + Isyn / 10.0f, v);
        const bool refr = rf > 0.0f;
        if (refr) vn = -65.0f;
        const float sn = (!refr && (vn > -50.0f)) ? 1.0f : 0.0f;
        const bool spk = sn > 0.5f;

        // publish at the EARLIEST instant: right after the spike decision.
        // This tag also tells my producer that ffd2 slot t%4 is consumable.
        const unsigned long long sm = __ballot(spk);
        if (lane == 0) {
            const unsigned long long tg =
                (unsigned long long)(unsigned int)(t + 1) << 32;
            unsigned long long* pp = mb2 + (size_t)((t + 1) & 1) * 1024
                                   + (size_t)b * 128
                                   + ((size_t)((slice << 2) | wv) << 1);
            __hip_atomic_store(&pp[0], tg | (sm & 0xFFFFFFFFULL),
                               __ATOMIC_RELAXED, __HIP_MEMORY_SCOPE_AGENT);
            __hip_atomic_store(&pp[1], tg | (sm >> 32),
                               __ATOMIC_RELAXED, __HIP_MEMORY_SCOPE_AGENT);
        }

        v  = spk ? -65.0f : vn;
        rf = spk ? rsteps : fmaxf(rf - 1.0f, 0.0f);
        out[((size_t)b * T_STEPS + t) * N_NEU + i] = sn;   // regular store
    }
}

extern "C" void kernel_launch(void* const* d_in, const int* in_sizes, int n_in,
                              void* d_out, int out_size, void* d_ws, size_t ws_size,
                              hipStream_t stream) {
    const float* inspk = (const float*)d_in[0];
    const float* W     = (const float*)d_in[1];
    const float* Wff   = (const float*)d_in[2];
    const float* sf    = (const float*)d_in[3];
    const float* sfff  = (const float*)d_in[4];
    const int*   ci    = (const int*)d_in[5];

    float* out = (float*)d_out;
    unsigned long long* tmask  = (unsigned long long*)((char*)d_ws + WS_TM_OFF);
    unsigned long long* mb2    = (unsigned long long*)((char*)d_ws + WS_MB_OFF);
    unsigned long long* ffmask = (unsigned long long*)((char*)d_ws + WS_FFM_OFF);
    unsigned long long* ffd2   = (unsigned long long*)((char*)d_ws + WS_FFD2_OFF);
    const int use_ffpre = (ws_size >= WS_NEED) ? 1 : 0;

    snn_init<<<64, 64, 0, stream>>>(ci, tmask, mb2);
    snn_ffmask<<<1000, 256, 0, stream>>>(inspk, ffmask, ffd2);
    const int grid = NBLK + (use_ffpre ? PROD_BLKS : 0);
    snn_run<<<grid, 256, 0, stream>>>(W, Wff, sf, sfff, ci, out,
                                      ffmask, tmask, ffd2, use_ffpre, mb2);
}

// Round 9
// 1621.047 us; speedup vs baseline: 3.3463x; 1.0011x over previous
//
#include <hip/hip_runtime.h>
#include <cstdint>
#include <cstddef>

// Problem constants
#define N_NEU   4096
#define N_IN    1024
#define B_SZ    8
#define T_STEPS 500
#define NSLICE  16
#define NBLK    (B_SZ * NSLICE)     // 128 blocks, 256 threads, 1 post/thread
#define FF_WORDS (B_SZ * T_STEPS * 16)

// ws layout:
//   [0)      u64 tmask[64]            512 B  (per-64-group exc-type bit masks)
//   [512)    u64 mb2[2][8][64][2]     16 KB  (tagged dbuf spike words:
//                                            (tag<<32)|mask_half, 2 halves/wave)
//   [17408)  u64 ffmask[B*T*16]       512 KB (input-spike bitmasks)
// No FF side-channel: R7/R8 proved bulk per-step data through agent-scope
// memory is poison (atomic stores write through to HBM; 128MB extra traffic,
// HBM-latency poll loads). FF drive is computed in-loop, issue/fold split.
#define WS_TM_OFF   0
#define WS_MB_OFF   512
#define WS_FFM_OFF  17408

__global__ __launch_bounds__(64) void snn_init(const int* __restrict__ ci,
                                               unsigned long long* __restrict__ tmask,
                                               unsigned long long* __restrict__ mb2) {
    const int k = blockIdx.x, l = threadIdx.x;   // 64 blocks x 64 threads
    unsigned long long m = __ballot(ci[(k << 6) + l] == 0);
    if (l == 0) tmask[k] = m;
    const int idx = (k << 6) + l;
    if (idx < 2048) mb2[idx] = 0ULL;             // tag 0 never matches t>=1
}

// input spikes (B,T,NI) -> bitmask words, 64 elems per word, ascending order
__global__ __launch_bounds__(256) void snn_ffmask(const float* __restrict__ inspk,
                                                  unsigned long long* __restrict__ ffmask) {
    int gid = blockIdx.x * 256 + threadIdx.x;
    int wid = gid >> 6, lane = gid & 63;
    int nw  = (gridDim.x * 256) >> 6;
    for (int w = wid; w < FF_WORDS; w += nw) {
        float v = inspk[(size_t)w * 64 + lane];
        unsigned long long m = __ballot(v > 0.5f);
        if (lane == 0) ffmask[w] = m;
    }
}

// Extract set-bit indices of a distributed 64x64-bit mask (lane l holds word l,
// bit b -> index l*64+b) into lds as typed entries (idx<<2)|ty, globally
// ascending; ty from tm_exc (bit set -> ty0/exc, clear -> ty1/inh). Pads to a
// multiple of 64 with sentinel entries (idx 0, ty 2). Returns real count.
__device__ __forceinline__ int extract_pad(unsigned long long m,
                                           unsigned long long tm_exc,
                                           int* lds, int lane) {
    int pc  = __popcll(m);
    int sum = pc;
#pragma unroll
    for (int d = 1; d < 64; d <<= 1) {
        int o = __shfl_up(sum, d, 64);
        if (lane >= d) sum += o;
    }
    int off   = sum - pc;           // exclusive prefix
    int total = __shfl(sum, 63, 64);
    int base  = lane << 6;
    while (m) {
        int bit = __builtin_ctzll(m);
        int ty  = ((tm_exc >> bit) & 1ULL) ? 0 : 1;
        lds[off++] = ((base + bit) << 2) | ty;
        m &= m - 1ULL;
    }
    int padcnt = (-total) & 63;
    if (lane < padcnt) lds[total + lane] = 2;   // sentinel: idx 0, ty 2
    return total;
}

// Combined typed gather: 64-deep pipelined loop over a padded entry list;
// exc/inh accumulate into SEPARATE accumulators (each internally ascending ->
// bit-exact vs reference's separate matmuls). Sentinels (ty2) contribute 0.
// List reads widened to int4 (ds_read_b128); accumulation order untouched.
__device__ __forceinline__ void gather2(const int* __restrict__ lst, int npad,
                                        const float* __restrict__ base,
                                        float se, float si,
                                        float* oe, float* oi) {
#pragma clang fp contract(off)
    float ae = 0.0f, ai = 0.0f;
    const int4* lst4 = (const int4*)lst;
    for (int k = 0; k < npad; k += 64) {
        int4  eq[16];
        int   e[64];
        float w[64];
#pragma unroll
        for (int u = 0; u < 16; ++u) eq[u] = lst4[(k >> 2) + u];
#pragma unroll
        for (int u = 0; u < 16; ++u) {
            e[4 * u + 0] = eq[u].x; e[4 * u + 1] = eq[u].y;
            e[4 * u + 2] = eq[u].z; e[4 * u + 3] = eq[u].w;
        }
#pragma unroll
        for (int u = 0; u < 64; ++u) w[u] = base[(size_t)(e[u] >> 2) << 12];
#pragma unroll
        for (int u = 0; u < 64; ++u) {
            const int ty = e[u] & 3;
            const float sc = (ty == 0) ? se : ((ty == 1) ? si : 0.0f);
            const float p  = w[u] * sc;           // per-element product rounding = W_eff
            ae = (ty == 0) ? ae + p : ae;
            ai = (ty == 1) ? ai + p : ai;
        }
    }
    *oe = ae; *oi = ai;
}

// FF issue: read chunk0's 64 entries (int4) from lds, ISSUE the 64 Wff loads
// into wf[] (registers). No FP math; consumption happens after the next poll.
__device__ __forceinline__ void ff_issue(const int* __restrict__ lds,
                                         const float* __restrict__ base,
                                         float* wf) {
    const int4* l4 = (const int4*)lds;
    int4 eq[16];
#pragma unroll
    for (int u = 0; u < 16; ++u) eq[u] = l4[u];
#pragma unroll
    for (int u = 0; u < 16; ++u) {
        wf[4 * u + 0] = base[(size_t)(eq[u].x >> 2) << 12];
        wf[4 * u + 1] = base[(size_t)(eq[u].y >> 2) << 12];
        wf[4 * u + 2] = base[(size_t)(eq[u].z >> 2) << 12];
        wf[4 * u + 3] = base[(size_t)(eq[u].w >> 2) << 12];
    }
}

// FF fold of chunk0: entries 0..nf-1 are real (ty0), nf..63 sentinels.
// af += w*sc ascending, sc=0 for sentinels -> identical op sequence to
// gather2(se=sff, si=0) on an all-ty0 list => bit-exact.
__device__ __forceinline__ float ff_fold(const float* wf, int nf, float sff) {
#pragma clang fp contract(off)
    float af = 0.0f;
#pragma unroll
    for (int u = 0; u < 64; ++u) {
        const float sc = (u < nf) ? sff : 0.0f;
        const float p  = wf[u] * sc;
        af += p;
    }
    return af;
}

__global__ __launch_bounds__(256) void snn_run(
    const float* __restrict__ W,       // (N,N) row j = presyn
    const float* __restrict__ Wff,     // (NI,N)
    const float* __restrict__ sf,      // (2,2)
    const float* __restrict__ sfff,    // (1,2)
    const int*   __restrict__ ci,      // (N)
    float*       __restrict__ out,     // (B,T,N)
    const unsigned long long* __restrict__ ffmask,
    const unsigned long long* __restrict__ tmask_g,
    unsigned long long* __restrict__ mb2)
{
#pragma clang fp contract(off)
    const int tid   = threadIdx.x;
    const int lane  = tid & 63;
    const int wv    = tid >> 6;
    const int bid   = blockIdx.x;
    // slice from bits {0,1,2,6}, batch from bits {3,4,5}
    const int slice = (((bid >> 6) & 1) << 3) | (bid & 7);
    const int b     = (bid >> 3) & 7;
    const int i     = (slice << 8) + (wv << 6) + lane;    // my post neuron
    const int c     = ci[i];

    const float s_exc = sf[c];
    const float s_inh = sf[2 + c];
    const float s_ff  = sfff[c];

    const unsigned long long my_tm = tmask_g[lane];

    // Per-wave private LDS regions: NO cross-wave sharing -> no barriers.
    __shared__ alignas(16) int lds_c[4][N_NEU + 64];
    __shared__ alignas(16) int lds_f[4][N_IN + 64];
    int* const my_ldsc = lds_c[wv];
    int* const my_ldsf = lds_f[wv];

    // mb2 layout (u64 units): [parity][batch][entry=(slice<<2)|wv][half]
    unsigned long long* const mbB = mb2 + (size_t)b * 128;

    float v = -70.0f, rf = 0.0f;
    float h0 = 0.0f, h1 = 0.0f, h2 = 0.0f, h3 = 0.0f;
    float g0 = 0.0f, g1 = 0.0f, g2 = 0.0f, g3 = 0.0f;

    const float aR0 = expf(-0.1f / 0.5f);
    const float aR1 = expf(-0.1f / 2.0f);
    const float aD0 = expf(-0.1f / 2.0f);
    const float aD1 = expf(-0.1f / 100.0f);
    const float aD2 = expf(-0.1f / 5.0f);
    const float kmem   = c ? (0.1f / 10.0f) : (0.1f / 20.0f);
    const float rsteps = c ? 10.0f : 20.0f;

    // warming base: this wave's 256B segment start within any W row
    const float* const wseg = W + (size_t)((slice << 8) + (wv << 6));
    const float* const wffb = Wff + i;

    // FF pipeline state: chunk0 loads held in registers across the poll.
    float wf[64];
    int   nf = 0;

    // prologue: FF(0) extract + issue (latency exposed once, no poll at t=0)
    {
        const unsigned long long mf =
            (lane < 16) ? ffmask[(size_t)b * T_STEPS * 16 + lane] : 0ULL;
        nf = extract_pad(mf, ~0ULL, my_ldsf, lane);
        if (nf > 0) ff_issue(my_ldsf, wffb, wf);
    }

    for (int t = 0; t < T_STEPS; ++t) {
        unsigned long long mw = 0ULL;
        if (t > 0) {
            // tagged single-hop poll, byte-identical to R6. The held wf[]
            // loads (issued last iteration) drain while we spin here.
            const unsigned int tg = (unsigned int)t;
            const unsigned long long* ep =
                mbB + (size_t)(t & 1) * 1024 + ((size_t)lane << 1);
            unsigned long long w0, w1;
            for (;;) {
                w0 = __hip_atomic_load(&ep[0], __ATOMIC_RELAXED,
                                       __HIP_MEMORY_SCOPE_AGENT);
                w1 = __hip_atomic_load(&ep[1], __ATOMIC_RELAXED,
                                       __HIP_MEMORY_SCOPE_AGENT);
                const bool ok = ((unsigned int)(w0 >> 32) == tg) &&
                                ((unsigned int)(w1 >> 32) == tg);
                if (__ballot(ok) == ~0ULL) break;
                __builtin_amdgcn_s_sleep(1);
            }
            mw = (w0 & 0xFFFFFFFFULL) | ((w1 & 0xFFFFFFFFULL) << 32);
            asm volatile("" ::: "memory");   // keep later mem ops below poll
        }

        // ---- FF fold: consume the pre-issued chunk0 loads (returned during
        // the poll -> ~zero stall). Rare nf>64 spill handled inline.
        float ffd = 0.0f;
        if (nf > 0) {
            ffd = ff_fold(wf, nf, s_ff);
            if (nf > 64) {
                const int npadf = (nf + 63) & ~63;
                for (int k = 64; k < npadf; k += 64) {
#pragma unroll
                    for (int u = 0; u < 64; ++u) {
                        const int e = my_ldsf[k + u];
                        const float w = wffb[(size_t)(e >> 2) << 12];
                        const float sc = ((e & 3) == 0) ? s_ff : 0.0f;
                        const float p  = w * sc;
                        ffd += p;
                    }
                }
            }
        }

        // ---- line warming: pull this step's W row-segments toward L1 while
        // the extract scan runs; real gather loads MSHR-merge.
        {
            unsigned long long mm = mw;
            float wacc = 0.0f;
            const size_t rowbase = (size_t)lane << 18;  // (lane*64)<<12 floats
            while (mm) {
                const int bit = __builtin_ctzll(mm); mm &= mm - 1ULL;
                const float* r = wseg + rowbase + ((size_t)bit << 12);
                wacc += r[0]; wacc += r[16]; wacc += r[32]; wacc += r[48];
            }
            asm volatile("" :: "v"(wacc));
        }

        // zero-skip: fully-silent network step -> no extract scan needed.
        int ne = 0;
        if (__ballot(mw != 0ULL) != 0ULL)
            ne = extract_pad(mw, my_tm, my_ldsc, lane);

        float exc, inh;
        gather2(my_ldsc, (ne + 63) & ~63, W + i, s_exc, s_inh, &exc, &inh);

        // ---- neuron update (identical fp op sequence to R0-R8: bit-exact) ----
        const float d0 = exc;
        const float d1 = 0.5f * exc;
        const float d2 = inh;
        const float d3 = ffd;

        h0 = fmaf(h0, aR0, d0);
        h1 = fmaf(h1, aR1, d1);
        h2 = fmaf(h2, aR0, d2);
        h3 = fmaf(h3, aR0, d3);
        g0 = fmaf(g0, aD0, (1.0f - aD0) * h0);
        g1 = fmaf(g1, aD1, (1.0f - aD1) * h1);
        g2 = fmaf(g2, aD2, (1.0f - aD2) * h2);
        g3 = fmaf(g3, aD0, (1.0f - aD0) * h3);

        const float p0 = g0 * (0.0f - v);
        const float p1 = g1 * (0.0f - v);
        const float p2 = g2 * (-80.0f - v);
        const float p3 = g3 * (0.0f - v);
        const float Isyn = ((p0 + p1) + p2) + p3;

        float vn = fmaf(kmem, (-70.0f - v) + Isyn / 10.0f, v);
        const bool refr = rf > 0.0f;
        if (refr) vn = -65.0f;
        const float sn = (!refr && (vn > -50.0f)) ? 1.0f : 0.0f;
        const bool spk = sn > 0.5f;

        // publish at the EARLIEST instant: right after the spike decision.
        const unsigned long long sm = __ballot(spk);
        if (lane == 0) {
            const unsigned long long tg =
                (unsigned long long)(unsigned int)(t + 1) << 32;
            unsigned long long* pp = mb2 + (size_t)((t + 1) & 1) * 1024
                                   + (size_t)b * 128
                                   + ((size_t)((slice << 2) | wv) << 1);
            __hip_atomic_store(&pp[0], tg | (sm & 0xFFFFFFFFULL),
                               __ATOMIC_RELAXED, __HIP_MEMORY_SCOPE_AGENT);
            __hip_atomic_store(&pp[1], tg | (sm >> 32),
                               __ATOMIC_RELAXED, __HIP_MEMORY_SCOPE_AGENT);
        }

        v  = spk ? -65.0f : vn;
        rf = spk ? rsteps : fmaxf(rf - 1.0f, 0.0f);
        out[((size_t)b * T_STEPS + t) * N_NEU + i] = sn;   // regular store

        // ---- free-window work (post-publish, pre-poll(t+1)): FF(t+1)
        // extract + issue. Poll(t+1) can't pass for ~500cy (visibility of
        // other blocks' publishes), so this VALU+issue work costs ~nothing;
        // the issued loads drain during the poll spin.
        if (t + 1 < T_STEPS) {
            const unsigned long long mf =
                (lane < 16) ? ffmask[((size_t)b * T_STEPS + (t + 1)) * 16 + lane]
                            : 0ULL;
            nf = extract_pad(mf, ~0ULL, my_ldsf, lane);
            if (nf > 0) ff_issue(my_ldsf, wffb, wf);
        }
    }
}

extern "C" void kernel_launch(void* const* d_in, const int* in_sizes, int n_in,
                              void* d_out, int out_size, void* d_ws, size_t ws_size,
                              hipStream_t stream) {
    const float* inspk = (const float*)d_in[0];
    const float* W     = (const float*)d_in[1];
    const float* Wff   = (const float*)d_in[2];
    const float* sf    = (const float*)d_in[3];
    const float* sfff  = (const float*)d_in[4];
    const int*   ci    = (const int*)d_in[5];

    float* out = (float*)d_out;
    unsigned long long* tmask  = (unsigned long long*)((char*)d_ws + WS_TM_OFF);
    unsigned long long* mb2    = (unsigned long long*)((char*)d_ws + WS_MB_OFF);
    unsigned long long* ffmask = (unsigned long long*)((char*)d_ws + WS_FFM_OFF);

    snn_init<<<64, 64, 0, stream>>>(ci, tmask, mb2);
    snn_ffmask<<<1000, 256, 0, stream>>>(inspk, ffmask);
    snn_run<<<NBLK, 256, 0, stream>>>(W, Wff, sf, sfff, ci, out,
                                      ffmask, tmask, mb2);
}